// Round 9
// baseline (177.663 us; speedup 1.0000x reference)
//
#include <hip/hip_runtime.h>
#include <hip/hip_fp16.h>
#include <hip/hip_cooperative_groups.h>

namespace cg = cooperative_groups;

// GCNConv: out = D^-1/2 (A + I) D^-1/2 (x W) + bias
// N = 10000, E = 640000, D_IN = D_OUT = 128, fp32 in/out.
//
// Round 9: three dispatches, zero global atomics.
//  K1 (non-coop, 64+313 blocks x 1024, disjoint ranges, NO interdependency):
//     blocks 0..63:   packed LDS histogram (out lo16 | in hi16),
//                     rank[e] = per-(b,c) in-rank (ushort)
//     blocks 64..376: g = bf16(x @ W)   UNSCALED (no dis dependency)
//  K2 (cooperative, 64 blocks x 1024 -- well under the 256-block coop cap
//     that killed round 8):
//     P1 reduce: dis[n] = rsqrt(1+outdeg); in-counts -> per-node exclusive
//        prefix over blocks (suboff, in place); indeg[n]. 157 active waves
//        spread over all 64 blocks, coalesced.
//     grid.sync()
//     P2 fill: csr[c*256 + suboff[b][c] + rank[e]] = src | fp16(dis[src])<<16
//  K3 gather: wave/node, half-wave = 2 edges/step; per edge one shfl'd uint
//     gives (src, w=dis[src]); acc += g[src]*w (FMA);
//     out = dis[c]*(acc + g[c]*dis[c]) + bias.

#define NNODES 10000
#define NB 64            // histogram / fill blocks
#define CAP 256          // CSR slots per node
#define HBLOCK 1024
#define GEMMB 313        // ceil(10000/32)

__device__ inline unsigned short f2bf(float f) {
    union { float f; unsigned u; } v; v.f = f;
    unsigned r = v.u + 0x7FFFu + ((v.u >> 16) & 1u);   // RNE
    return (unsigned short)(r >> 16);
}
__device__ inline float bf2f(unsigned short h) {
    union { unsigned u; float f; } v; v.u = ((unsigned)h) << 16; return v.f;
}

// K1: hist (blocks 0..63) || gemm (blocks 64..376) — independent halves.
__global__ __launch_bounds__(HBLOCK) void histgemm_kernel(
    const int* __restrict__ row, const int* __restrict__ col,
    int* __restrict__ partial, unsigned short* __restrict__ rank,
    const float* __restrict__ x, const float* __restrict__ W,
    unsigned short* __restrict__ g, int N, int E, int EPB) {
    __shared__ int lds[NNODES];
    const int tid = threadIdx.x, b = blockIdx.x;

    if (b < NB) {
        for (int j = tid; j < N; j += HBLOCK) lds[j] = 0;
        __syncthreads();
        const int e0 = b * EPB, e1 = min(E, e0 + EPB);
        for (int e = e0 + tid; e < e1; e += HBLOCK) {
            int r = row[e], c = col[e];
            atomicAdd(&lds[r], 1);                                   // out lo16
            unsigned old = atomicAdd((unsigned*)&lds[c], 0x10000u);  // in hi16
            rank[e] = (unsigned short)(old >> 16);
        }
        __syncthreads();
        for (int j = tid; j < N; j += HBLOCK) partial[b * N + j] = lds[j];
    } else {
        // gemm: g = bf16(x @ W), 32 rows/block, UNSCALED
        float* xs = (float*)lds;                       // 16 KB of the 40 KB
        const int rowBase = (b - NB) * 32;
        for (int idx = tid; idx < 32 * 128; idx += HBLOCK) {
            int r = rowBase + (idx >> 7);
            xs[idx] = (r < N) ? x[r * 128 + (idx & 127)] : 0.0f;
        }
        __syncthreads();
        const int lr = tid >> 5, c4 = tid & 31;
        const int rr = rowBase + lr;
        const float4* __restrict__ W4 = (const float4*)W;
        float4 acc = make_float4(0.f, 0.f, 0.f, 0.f);
#pragma unroll 8
        for (int k = 0; k < 128; ++k) {
            float xv = xs[lr * 128 + k];
            float4 wv = W4[k * 32 + c4];
            acc.x = fmaf(xv, wv.x, acc.x);
            acc.y = fmaf(xv, wv.y, acc.y);
            acc.z = fmaf(xv, wv.z, acc.z);
            acc.w = fmaf(xv, wv.w, acc.w);
        }
        if (rr < N) {
            ushort4 o;
            o.x = f2bf(acc.x); o.y = f2bf(acc.y);
            o.z = f2bf(acc.z); o.w = f2bf(acc.w);
            ((ushort4*)g)[rr * 32 + c4] = o;
        }
    }
}

// K2 (cooperative, 64 blocks): reduce -> grid.sync -> fill.
__global__ __launch_bounds__(HBLOCK) void coop_prep_kernel(
    const int* __restrict__ row, const int* __restrict__ col,
    int* __restrict__ partial, const unsigned short* __restrict__ rank,
    float* __restrict__ dis, int* __restrict__ indeg,
    unsigned* __restrict__ csr, int N, int E, int EPB) {
    __shared__ int lds[NNODES];
    cg::grid_group grid = cg::this_grid();
    const int tid = threadIdx.x, b = blockIdx.x;

    // ---- P1: reduce, spread over all 64 blocks (157 active waves) ----
    {
        const int gw = (b << 4) + (tid >> 6);   // global wave id, 16 waves/block
        const int lane = tid & 63;
        const int n = gw * 64 + lane;
        if (n < N) {
            int s = 0, run = 0;
#pragma unroll 8
            for (int bb = 0; bb < NB; ++bb) {
                int v = partial[bb * N + n];
                s += v & 0xFFFF;
                partial[bb * N + n] = run;             // becomes suboff[bb][n]
                run += ((unsigned)v) >> 16;
            }
            dis[n] = rsqrtf(1.0f + (float)s);
            indeg[n] = run;
        }
    }
    grid.sync();

    // ---- P2: fill — csr[c*CAP + suboff[b][c] + rank[e]] = src | h(dis[src])<<16
    for (int j = tid; j < N; j += HBLOCK)
        lds[j] = (j << 8) + partial[b * N + j];
    __syncthreads();
    const int e0 = b * EPB, e1 = min(E, e0 + EPB);
    for (int e = e0 + tid; e < e1; e += HBLOCK) {
        int r = row[e], c = col[e];
        unsigned hw = __half_as_ushort(__float2half_rn(dis[r]));
        csr[lds[c] + (int)rank[e]] = (unsigned)r | (hw << 16);
    }
}

// K3: one wave per destination node. half = lane>>5 picks one of 2 edges
// per step; l32 = lane&31 picks the 4-col bf16 chunk (32 x 8B = 256B row).
__global__ void gather_kernel(const int* __restrict__ indeg,
                              const unsigned* __restrict__ csr,
                              const unsigned short* __restrict__ g,
                              const float* __restrict__ dis,
                              const float* __restrict__ bias,
                              float* __restrict__ out, int n) {
    const int wave = (blockIdx.x * blockDim.x + threadIdx.x) >> 6;
    const int lane = threadIdx.x & 63;
    if (wave >= n) return;
    const int c = wave;
    const int half = lane >> 5;
    const int l32 = lane & 31;
    const ushort4* __restrict__ g4 = (const ushort4*)g;

    const float dc = dis[c];
    float4 acc = make_float4(0.f, 0.f, 0.f, 0.f);
    if (half == 0) {   // self-loop: + g[c] * dis[c]
        ushort4 gv = g4[c * 32 + l32];
        acc.x = fmaf(bf2f(gv.x), dc, acc.x);
        acc.y = fmaf(bf2f(gv.y), dc, acc.y);
        acc.z = fmaf(bf2f(gv.z), dc, acc.z);
        acc.w = fmaf(bf2f(gv.w), dc, acc.w);
    }

    const int start = c << 8;              // c * CAP
    const int end = start + indeg[c];
    for (int base = start; base < end; base += 64) {
        int idx = base + lane;
        unsigned packed = (idx < end) ? csr[idx] : 0u;
        int cnt = min(64, end - base);
#pragma unroll
        for (int t = 0; t < 64; t += 2) {
            int j = t + half;              // half 0: even edges, half 1: odd
            unsigned pk = (unsigned)__shfl((int)packed, j);
            if (j < cnt) {
                int r = (int)(pk & 0xFFFFu);
                float w = __half2float(__ushort_as_half((unsigned short)(pk >> 16)));
                ushort4 gv = g4[r * 32 + l32];
                acc.x = fmaf(bf2f(gv.x), w, acc.x);
                acc.y = fmaf(bf2f(gv.y), w, acc.y);
                acc.z = fmaf(bf2f(gv.z), w, acc.z);
                acc.w = fmaf(bf2f(gv.w), w, acc.w);
            }
        }
    }
    float ox = acc.x + __shfl(acc.x, l32 + 32);
    float oy = acc.y + __shfl(acc.y, l32 + 32);
    float oz = acc.z + __shfl(acc.z, l32 + 32);
    float ow = acc.w + __shfl(acc.w, l32 + 32);
    if (lane < 32) {
        float4 bv = ((const float4*)bias)[l32];
        float4 o;
        o.x = fmaf(ox, dc, bv.x);
        o.y = fmaf(oy, dc, bv.y);
        o.z = fmaf(oz, dc, bv.z);
        o.w = fmaf(ow, dc, bv.w);
        ((float4*)out)[c * 32 + l32] = o;
    }
}

extern "C" void kernel_launch(void* const* d_in, const int* in_sizes, int n_in,
                              void* d_out, int out_size, void* d_ws, size_t ws_size,
                              hipStream_t stream) {
    const float* x    = (const float*)d_in[0];
    const int*   ei   = (const int*)d_in[1];
    const float* W    = (const float*)d_in[2];
    const float* bias = (const float*)d_in[3];
    float* out = (float*)d_out;

    int N = in_sizes[0] / 128;     // 10000
    int E = in_sizes[1] / 2;       // 640000
    const int* row = ei;
    const int* col = ei + E;
    int EPB = (E + NB - 1) / NB;   // 10000

    // Workspace (~17 MB):
    auto align256 = [](size_t v) { return (v + 255) & ~(size_t)255; };
    char* p = (char*)d_ws;
    int*            partial = (int*)p;            p += align256((size_t)NB * N * 4);   // 2.56 MB
    unsigned short* rank    = (unsigned short*)p; p += align256((size_t)E * 2);        // 1.28 MB
    float*          dis     = (float*)p;          p += align256((size_t)N * 4);
    int*            indeg   = (int*)p;            p += align256((size_t)N * 4);
    unsigned*       csr     = (unsigned*)p;       p += align256((size_t)N * CAP * 4);  // 10.24 MB
    unsigned short* g       = (unsigned short*)p; p += align256((size_t)N * 128 * 2);  // 2.56 MB

    histgemm_kernel<<<NB + GEMMB, HBLOCK, 0, stream>>>(
        row, col, partial, rank, x, W, g, N, E, EPB);

    void* args[] = {(void*)&row, (void*)&col, (void*)&partial, (void*)&rank,
                    (void*)&dis, (void*)&indeg, (void*)&csr,
                    (void*)&N, (void*)&E, (void*)&EPB};
    hipLaunchCooperativeKernel((void*)coop_prep_kernel, dim3(NB), dim3(HBLOCK),
                               args, 0, stream);

    long long gthreads = (long long)N * 64;
    gather_kernel<<<(int)((gthreads + 255) / 256), 256, 0, stream>>>(
        indeg, csr, g, dis, bias, out, N);
}